// Round 3
// baseline (1218.004 us; speedup 1.0000x reference)
//
#include <hip/hip_runtime.h>
#include <hip/hip_bf16.h>
#include <cstdint>

#define BATCH   4096
#define IN_DIM  1024
#define OUT_DIM 1024
#define NEXP    16

typedef __bf16 bf16;
typedef __attribute__((ext_vector_type(8))) __bf16 bf16x8;
typedef __attribute__((ext_vector_type(4))) float  f32x4;

#define AS1 __attribute__((address_space(1)))
#define AS3 __attribute__((address_space(3)))

__device__ __forceinline__ void gld_lds16(const bf16* g, bf16* l) {
    __builtin_amdgcn_global_load_lds((const AS1 void*)g, (AS3 void*)l, 16, 0, 0);
}

// Counted wait + barrier in ONE asm with a "memory" clobber — mirrors the
// codegen shape of __syncthreads (which R0 proved clean), with the drain
// count N instead of 0 so prefetches stay in flight across the barrier.
#define WB(N) asm volatile("s_waitcnt vmcnt(" #N ")\n\ts_barrier" ::: "memory")

// ---------------------------------------------------------------------------
// Merged conversion kernel (unchanged).
// Blocks [0,4096): weight fp32 -> fragment-ordered bf16 tiles via LDS
//   transpose (coalesced f32x4 row reads).
// Blocks [4096,4608): x fp32 -> 512 pre-tiled swizzled bf16 images.
// ---------------------------------------------------------------------------
__global__ __launch_bounds__(256) void convert_all(
        const float* __restrict__ x, const float* __restrict__ W,
        bf16* __restrict__ xt, bf16* __restrict__ wt) {
    __shared__ float Ls[64][65];       // pad 65: read phase is 2-way (free)
    int t = threadIdx.x;
    int bid = blockIdx.x;
    if (bid < 4096) {
        int nblk = bid >> 8, ne = (bid >> 4) & 15, ks = bid & 15;
        int kb = ne * 1024 + ks * 64;
        int n0 = nblk * 64;
#pragma unroll
        for (int r = 0; r < 4; r++) {
            int idx = r * 256 + t;             // 1024 f32x4 = 64x64 tile
            int row = idx >> 4, c4 = (idx & 15) * 4;
            f32x4 v = *(const f32x4*)(W + (size_t)(kb + row) * OUT_DIM + n0 + c4);
#pragma unroll
            for (int j = 0; j < 4; j++) Ls[row][c4 + j] = v[j];
        }
        __syncthreads();
#pragma unroll
        for (int r = 0; r < 2; r++) {
            int c = r * 256 + t;               // 0..511
            int sub = c >> 6, l = c & 63;
            int lr = l & 15, lq = l >> 4;
            int kk = sub >> 2, wn = (sub >> 1) & 1, nt = sub & 1;
            int krow = kk * 32 + lq * 8;
            int col = wn * 32 + nt * 16 + lr;
            bf16x8 v;
#pragma unroll
            for (int j = 0; j < 8; j++) v[j] = (bf16)Ls[krow + j][col];
            *(bf16x8*)(wt + (size_t)bid * 4096 + c * 8) = v;
        }
    } else {
        int tile = bid - 4096;                 // 512
        int mblk = tile >> 4, ks = tile & 15;
#pragma unroll
        for (int r = 0; r < 4; r++) {
            int q = r * 256 + t;
            int m_loc = q >> 3, sc = q & 7;
            int cc = sc ^ (m_loc & 7);
            const float* src = x + (size_t)(mblk * 128 + m_loc) * IN_DIM + ks * 64 + cc * 8;
            f32x4 a = *(const f32x4*)src;
            f32x4 b = *(const f32x4*)(src + 4);
            bf16x8 v;
#pragma unroll
            for (int j = 0; j < 4; j++) { v[j] = (bf16)a[j]; v[4 + j] = (bf16)b[j]; }
            *(bf16x8*)(xt + (size_t)tile * 8192 + q * 8) = v;
        }
    }
}

// ---------------------------------------------------------------------------
// GEMM: minimal-delta pipelining of the proven R0 structure.
// Step t = ks*16 + ne. Bs has 4 buffers, prefetch DISTANCE 1:
//   step t: [issue B(t+1) -> Bs[(t+1)&3]]  [vmcnt(2); s_barrier]  [compute Bs[t&3]]
// WAR safety: a wave at issue(t) has passed barrier#(t-1); any straggler is
// at worst inside compute(t-1), reading Bs[(t-1)&3] != Bs[(t+1)&3].
// Publish safety: every wave waits its own in-order vmcnt(2) (covering its
// B(t) loads, issued at t-1) BEFORE barrier#t, so barrier#t publishes B(t).
// A is single-buffered: A(ks+1) issued at ne==1 AFTER the barrier (all waves
// finished the ne==0 af reads), consumed 15 steps later; its 4 loads are
// drained by the in-order vmcnt(2) at ne==3 (hence ne==2 uses vmcnt(6)).
// Only vmcnt(0) in the whole kernel: prologue + final step.
// Block 128m x 64n, 4 waves (2x2), wave tile 64x32, mfma 16x16x32 bf16.
// LDS 56.8 KB; grid 512 = 2 blocks/CU (grid-limited, same as R0).
// ---------------------------------------------------------------------------
__global__ __launch_bounds__(256, 3) void moe_gemm(
        const float* __restrict__ cw, const float* __restrict__ bias,
        const bf16* __restrict__ xt, const bf16* __restrict__ wt,
        float* __restrict__ out) {
    int nblk = blockIdx.x;                 // 16
    int mblk = blockIdx.y;                 // 32
    int m0 = mblk * 128, n0 = nblk * 64;
    int t = threadIdx.x;
    int lane = t & 63, w = t >> 6;
    int wm = w >> 1, wn = w & 1;
    int lq = lane >> 4, lr = lane & 15;

    __shared__ bf16 As[128 * 64];          // 16 KB swizzled A image (single)
    __shared__ bf16 Bs[4][64 * 64];        // 4 x 8 KB fragment-ordered B tiles
    __shared__ float cwT[16 * 132];        // cwT[ne][row], stride 132 (banks)

    // transpose cw panel into LDS once
#pragma unroll
    for (int r = 0; r < 2; r++) {
        int q = r * 256 + t;               // 512 f32x4 = 2048 floats
        f32x4 v = *(const f32x4*)(cw + (size_t)m0 * NEXP + q * 4);
        int row = q >> 2, nb = (q & 3) * 4;
#pragma unroll
        for (int c2 = 0; c2 < 4; c2++) cwT[(nb + c2) * 132 + row] = v[c2];
    }
    __syncthreads();

    const bf16* abase = xt + (size_t)(mblk * 16) * 8192;
    const bf16* bbase = wt + (size_t)nblk * (16 * 16 * 4096);

    // prologue: stage A(ks=0) + B(t=0), full drain once
    {
        const bf16* a0 = abase + t * 8;
#pragma unroll
        for (int r = 0; r < 4; r++) gld_lds16(a0 + r * 2048, &As[r * 2048 + t * 8]);
        const bf16* b0 = bbase + t * 8;    // tile (ne=0, ks=0)
        gld_lds16(b0, &Bs[0][t * 8]);
        gld_lds16(b0 + 2048, &Bs[0][2048 + t * 8]);
    }
    WB(0);

    const f32x4 fz = {0.f, 0.f, 0.f, 0.f};
    f32x4 acc[4][2];
#pragma unroll
    for (int mt = 0; mt < 4; mt++)
#pragma unroll
        for (int nt = 0; nt < 2; nt++) acc[mt][nt] = fz;

    int swz = lr & 7;
    int mrow[4];
#pragma unroll
    for (int mt = 0; mt < 4; mt++) mrow[mt] = (wm * 64 + mt * 16 + lr) * 64;

    bf16x8 af[4][2];                       // A frags, live across one ks

#pragma unroll 1
    for (int ks = 0; ks < 16; ks++) {
#pragma unroll
        for (int ne = 0; ne < 16; ne++) {
            // ---- issue B(t+1), distance 1 (skip only at the very last step)
            if (ne < 15) {
                const bf16* bn = bbase + (size_t)((ne + 1) * 16 + ks) * 4096 + t * 8;
                bf16* bd = &Bs[(ne + 1) & 3][t * 8];
                gld_lds16(bn, bd);
                gld_lds16(bn + 2048, bd + 2048);
            } else if (ks < 15) {          // t%16==15: next ks' ne=0 tile -> buf 0
                const bf16* bn = bbase + (size_t)(ks + 1) * 4096 + t * 8;
                bf16* bd = &Bs[0][t * 8];
                gld_lds16(bn, bd);
                gld_lds16(bn + 2048, bd + 2048);
            }
            // ---- counted wait + barrier (one asm, "memory" clobber)
            if (ne == 2) {
                if (ks < 15) WB(6);        // A' (4 loads) + B(t+1) in flight
                else         WB(2);        // no A' on last ks
            } else if (ne == 15) {
                if (ks < 15) WB(2);
                else         WB(0);        // final step: drain B(255)
            } else {
                WB(2);
            }
            // ---- A(ks+1) prefetch, AFTER the barrier: all waves have
            //      finished the ne==0 af reads of As, so overwrite is safe.
            if (ne == 1 && ks < 15) {
                const bf16* an = abase + (size_t)(ks + 1) * 8192 + t * 8;
                gld_lds16(an,        &As[t * 8]);
                gld_lds16(an + 2048, &As[2048 + t * 8]);
                gld_lds16(an + 4096, &As[4096 + t * 8]);
                gld_lds16(an + 6144, &As[6144 + t * 8]);
            }
            // ---- A fragments -> registers, reused across all 16 experts
            if (ne == 0) {
#pragma unroll
                for (int kk = 0; kk < 2; kk++)
#pragma unroll
                    for (int mt = 0; mt < 4; mt++)
                        af[mt][kk] = *(const bf16x8*)
                            &As[mrow[mt] + ((kk * 4 + lq) ^ swz) * 8];
            }
            // ---- B fragments (linear, conflict-free)
            bf16x8 bfr[2][2];
#pragma unroll
            for (int kk = 0; kk < 2; kk++)
#pragma unroll
                for (int nt = 0; nt < 2; nt++)
                    bfr[kk][nt] = *(const bf16x8*)
                        &Bs[ne & 3][((kk * 2 + wn) * 2 + nt) * 512 + lane * 8];
            // ---- scales for this expert (broadcast within quads)
            f32x4 s[4];
#pragma unroll
            for (int mt = 0; mt < 4; mt++)
                s[mt] = *(const f32x4*)&cwT[ne * 132 + wm * 64 + mt * 16 + lq * 4];
            // ---- MFMA + immediate fold
#pragma unroll
            for (int mt = 0; mt < 4; mt++)
#pragma unroll
                for (int nt = 0; nt < 2; nt++) {
                    f32x4 p = __builtin_amdgcn_mfma_f32_16x16x32_bf16(
                        af[mt][0], bfr[0][nt], fz, 0, 0, 0);
                    p = __builtin_amdgcn_mfma_f32_16x16x32_bf16(
                        af[mt][1], bfr[1][nt], p, 0, 0, 0);
                    acc[mt][nt] += s[mt] * p;   // v_pk_fma_f32 x2
                }
        }
    }

    // ---- bias: one MFMA k-step, operands loaded straight to registers ----
    {
        bf16x8 acw[4];
#pragma unroll
        for (int mt = 0; mt < 4; mt++) {
            bf16x8 v;
#pragma unroll
            for (int j = 0; j < 8; j++) v[j] = (bf16)0.f;
            if (lq < 2) {                  // k = lq*8+j in 0..15 real, else 0
                int row = m0 + wm * 64 + mt * 16 + lr;
                f32x4 a = *(const f32x4*)(cw + (size_t)row * NEXP + lq * 8);
                f32x4 b = *(const f32x4*)(cw + (size_t)row * NEXP + lq * 8 + 4);
#pragma unroll
                for (int j = 0; j < 4; j++) { v[j] = (bf16)a[j]; v[4 + j] = (bf16)b[j]; }
            }
            acw[mt] = v;
        }
        bf16x8 bb[2];
#pragma unroll
        for (int nt = 0; nt < 2; nt++) {
            bf16x8 v;
#pragma unroll
            for (int j = 0; j < 8; j++) v[j] = (bf16)0.f;
            if (lq < 2) {
                int col = n0 + wn * 32 + nt * 16 + lr;
#pragma unroll
                for (int j = 0; j < 8; j++)
                    v[j] = (bf16)bias[(size_t)(lq * 8 + j) * OUT_DIM + col];
            }
            bb[nt] = v;
        }
#pragma unroll
        for (int mt = 0; mt < 4; mt++)
#pragma unroll
            for (int nt = 0; nt < 2; nt++)
                acc[mt][nt] = __builtin_amdgcn_mfma_f32_16x16x32_bf16(
                    acw[mt], bb[nt], acc[mt][nt], 0, 0, 0);
    }

    // epilogue: relu + store (C/D: col = lane&15, row = quad*4 + reg)
#pragma unroll
    for (int mt = 0; mt < 4; mt++) {
        int row = m0 + wm * 64 + mt * 16 + lq * 4;
#pragma unroll
        for (int nt = 0; nt < 2; nt++) {
            int col = n0 + wn * 32 + nt * 16 + lr;
#pragma unroll
            for (int r2 = 0; r2 < 4; r2++) {
                float v = acc[mt][nt][r2];
                out[(size_t)(row + r2) * OUT_DIM + col] = v > 0.f ? v : 0.f;
            }
        }
    }
}

// ---------------------------------------------------------------------------
// Insurance fallback if ws_size is too small.
// ---------------------------------------------------------------------------
__global__ void fallback_kernel(const float* __restrict__ x, const float* __restrict__ cw,
                                const float* __restrict__ W, const float* __restrict__ bias,
                                float* __restrict__ out) {
    int o = blockIdx.x * 256 + threadIdx.x;
    int b = o >> 10, oc = o & 1023;
    const float* xr = x + (size_t)b * IN_DIM;
    float accv = 0.f;
    for (int n = 0; n < NEXP; n++) {
        const float* wr = W + (size_t)n * IN_DIM * OUT_DIM + oc;
        float z = 0.f;
        for (int i = 0; i < IN_DIM; i++) z += xr[i] * wr[(size_t)i * OUT_DIM];
        accv += cw[(size_t)b * NEXP + n] * (z + bias[n * OUT_DIM + oc]);
    }
    out[o] = accv > 0.f ? accv : 0.f;
}

extern "C" void kernel_launch(void* const* d_in, const int* in_sizes, int n_in,
                              void* d_out, int out_size, void* d_ws, size_t ws_size,
                              hipStream_t stream) {
    const float* x    = (const float*)d_in[0];
    const float* cw   = (const float*)d_in[1];
    const float* W    = (const float*)d_in[2];
    const float* bias = (const float*)d_in[3];
    float* out = (float*)d_out;

    const size_t wt_elems = (size_t)NEXP * IN_DIM * OUT_DIM;   // 32 MB bf16
    const size_t xt_elems = (size_t)BATCH * IN_DIM;            // 8 MB bf16
    if (ws_size < (wt_elems + xt_elems) * sizeof(bf16)) {
        fallback_kernel<<<(BATCH * OUT_DIM) / 256, 256, 0, stream>>>(x, cw, W, bias, out);
        return;
    }
    bf16* wt = (bf16*)d_ws;
    bf16* xt = wt + wt_elems;

    convert_all<<<4096 + 512, 256, 0, stream>>>(x, W, xt, wt);
    moe_gemm<<<dim3(16, 32), 256, 0, stream>>>(cw, bias, xt, wt, out);
}

// Round 4
// 260.153 us; speedup vs baseline: 4.6819x; 4.6819x over previous
//
#include <hip/hip_runtime.h>
#include <hip/hip_bf16.h>
#include <cstdint>

#define BATCH   4096
#define IN_DIM  1024
#define OUT_DIM 1024
#define NEXP    16

typedef __bf16 bf16;
typedef __attribute__((ext_vector_type(8))) __bf16 bf16x8;
typedef __attribute__((ext_vector_type(4))) float  f32x4;

#define AS1 __attribute__((address_space(1)))
#define AS3 __attribute__((address_space(3)))

__device__ __forceinline__ void gld_lds16(const bf16* g, bf16* l) {
    __builtin_amdgcn_global_load_lds((const AS1 void*)g, (AS3 void*)l, 16, 0, 0);
}

// ---------------------------------------------------------------------------
// Merged conversion kernel (unchanged from R2/R3 — this part was clean).
// Blocks [0,4096): weight fp32 -> fragment-ordered bf16 tiles via LDS
//   transpose (coalesced f32x4 row reads).
// Blocks [4096,4608): x fp32 -> 512 pre-tiled swizzled bf16 images.
// ---------------------------------------------------------------------------
__global__ __launch_bounds__(256) void convert_all(
        const float* __restrict__ x, const float* __restrict__ W,
        bf16* __restrict__ xt, bf16* __restrict__ wt) {
    __shared__ float Ls[64][65];       // pad 65: read phase is 2-way (free)
    int t = threadIdx.x;
    int bid = blockIdx.x;
    if (bid < 4096) {
        int nblk = bid >> 8, ne = (bid >> 4) & 15, ks = bid & 15;
        int kb = ne * 1024 + ks * 64;
        int n0 = nblk * 64;
#pragma unroll
        for (int r = 0; r < 4; r++) {
            int idx = r * 256 + t;             // 1024 f32x4 = 64x64 tile
            int row = idx >> 4, c4 = (idx & 15) * 4;
            f32x4 v = *(const f32x4*)(W + (size_t)(kb + row) * OUT_DIM + n0 + c4);
#pragma unroll
            for (int j = 0; j < 4; j++) Ls[row][c4 + j] = v[j];
        }
        __syncthreads();
#pragma unroll
        for (int r = 0; r < 2; r++) {
            int c = r * 256 + t;               // 0..511
            int sub = c >> 6, l = c & 63;
            int lr = l & 15, lq = l >> 4;
            int kk = sub >> 2, wn = (sub >> 1) & 1, nt = sub & 1;
            int krow = kk * 32 + lq * 8;
            int col = wn * 32 + nt * 16 + lr;
            bf16x8 v;
#pragma unroll
            for (int j = 0; j < 8; j++) v[j] = (bf16)Ls[krow + j][col];
            *(bf16x8*)(wt + (size_t)bid * 4096 + c * 8) = v;
        }
    } else {
        int tile = bid - 4096;                 // 512
        int mblk = tile >> 4, ks = tile & 15;
#pragma unroll
        for (int r = 0; r < 4; r++) {
            int q = r * 256 + t;
            int m_loc = q >> 3, sc = q & 7;
            int cc = sc ^ (m_loc & 7);
            const float* src = x + (size_t)(mblk * 128 + m_loc) * IN_DIM + ks * 64 + cc * 8;
            f32x4 a = *(const f32x4*)src;
            f32x4 b = *(const f32x4*)(src + 4);
            bf16x8 v;
#pragma unroll
            for (int j = 0; j < 4; j++) { v[j] = (bf16)a[j]; v[4 + j] = (bf16)b[j]; }
            *(bf16x8*)(xt + (size_t)tile * 8192 + q * 8) = v;
        }
    }
}

// ---------------------------------------------------------------------------
// GEMM: R0's proven-clean structure (__syncthreads only, no inline asm, no
// sched_barrier/setprio, launch_bounds(256,3)), with ONE change: TWO experts
// per barrier instead of one. 4 B-buffers (32 KB):
//   step s (s=0..7 per ks): prefetch experts 2s+2,2s+3 into bufs {2,3}/{0,1},
//   compute experts 2s,2s+1 from bufs {0,1}/{2,3}, __syncthreads.
// Barriers per ks: 1 (stage) + 8 (steps) = 9 vs R0's 17 -> 144 total vs 272,
// and each drain now has ~2x the compute (32 MFMA) covering the in-flight
// prefetch. WAR: prefetch targets bufs last READ in step s-1, published by
// that step's barrier. Publish: __syncthreads' vmcnt(0) drain at end of the
// issuing step, before any consumer. All buffer indices compile-time under
// #pragma unroll 2 (bodies pair as {0,1}/{2,3}).
// Block 128m x 64n, 4 waves (2x2), wave tile 64x32, mfma 16x16x32 bf16.
// LDS 56.25 KB -> 2 blocks/CU (grid 512 = 2/CU, grid-limited same as R0).
// ---------------------------------------------------------------------------
__global__ __launch_bounds__(256, 3) void moe_gemm(
        const float* __restrict__ cw, const float* __restrict__ bias,
        const bf16* __restrict__ xt, const bf16* __restrict__ wt,
        float* __restrict__ out) {
    int nblk = blockIdx.x;                 // 16 -> bid%8 clusters nblk per XCD
    int mblk = blockIdx.y;                 // 32
    int m0 = mblk * 128, n0 = nblk * 64;
    int t = threadIdx.x;
    int lane = t & 63, w = t >> 6;
    int wm = w >> 1, wn = w & 1;
    int lq = lane >> 4, lr = lane & 15;

    __shared__ bf16 As[128 * 64];          // 16 KB swizzled A image
    __shared__ bf16 Bs[4][64 * 64];        // 4 x 8 KB fragment-ordered B tiles
    __shared__ float cwT[16 * 132];        // cwT[ne][row], stride 132 (banks)

    // transpose cw panel into LDS once
#pragma unroll
    for (int r = 0; r < 2; r++) {
        int q = r * 256 + t;               // 512 f32x4 = 2048 floats
        f32x4 v = *(const f32x4*)(cw + (size_t)m0 * NEXP + q * 4);
        int row = q >> 2, nb = (q & 3) * 4;
#pragma unroll
        for (int c2 = 0; c2 < 4; c2++) cwT[(nb + c2) * 132 + row] = v[c2];
    }

    const f32x4 fz = {0.f, 0.f, 0.f, 0.f};
    f32x4 acc[4][2];
#pragma unroll
    for (int mt = 0; mt < 4; mt++)
#pragma unroll
        for (int nt = 0; nt < 2; nt++) acc[mt][nt] = fz;

    int swz = lr & 7;
    int mrow[4];
#pragma unroll
    for (int mt = 0; mt < 4; mt++) mrow[mt] = (wm * 64 + mt * 16 + lr) * 64;

    const bf16* abase = xt + (size_t)(mblk * 16) * 8192;
    const bf16* bbase = wt + (size_t)nblk * (16 * 16 * 4096);

    for (int ks = 0; ks < 16; ks++) {
        // stage A tile (16 KB) + B tiles for ne=0,1; one drain barrier
        const bf16* asrc = abase + (size_t)ks * 8192 + t * 8;
#pragma unroll
        for (int r = 0; r < 4; r++) gld_lds16(asrc + r * 2048, &As[r * 2048 + t * 8]);
        const bf16* b0 = bbase + (size_t)ks * 4096 + t * 8;          // ne = 0
        gld_lds16(b0,        &Bs[0][t * 8]);
        gld_lds16(b0 + 2048, &Bs[0][2048 + t * 8]);
        const bf16* b1 = bbase + (size_t)(16 + ks) * 4096 + t * 8;   // ne = 1
        gld_lds16(b1,        &Bs[1][t * 8]);
        gld_lds16(b1 + 2048, &Bs[1][2048 + t * 8]);
        __syncthreads();

        // A fragments -> registers, reused across all 16 experts
        bf16x8 af[4][2];
#pragma unroll
        for (int kk = 0; kk < 2; kk++)
#pragma unroll
            for (int mt = 0; mt < 4; mt++)
                af[mt][kk] = *(const bf16x8*)&As[mrow[mt] + ((kk * 4 + lq) ^ swz) * 8];

#pragma unroll 2
        for (int s = 0; s < 8; s++) {
            int nbase = s * 2;
            if (s < 7) {                   // prefetch experts nbase+2, nbase+3
                const bf16* bn2 = bbase + (size_t)((nbase + 2) * 16 + ks) * 4096 + t * 8;
                bf16* bd2 = &Bs[(nbase + 2) & 3][t * 8];
                gld_lds16(bn2,        bd2);
                gld_lds16(bn2 + 2048, bd2 + 2048);
                const bf16* bn3 = bbase + (size_t)((nbase + 3) * 16 + ks) * 4096 + t * 8;
                bf16* bd3 = &Bs[(nbase + 3) & 3][t * 8];
                gld_lds16(bn3,        bd3);
                gld_lds16(bn3 + 2048, bd3 + 2048);
            }
#pragma unroll
            for (int e = 0; e < 2; e++) {
                int ne = nbase + e;
                // B fragments (linear, conflict-free)
                bf16x8 bfr[2][2];
#pragma unroll
                for (int kk = 0; kk < 2; kk++)
#pragma unroll
                    for (int nt = 0; nt < 2; nt++)
                        bfr[kk][nt] = *(const bf16x8*)
                            &Bs[ne & 3][((kk * 2 + wn) * 2 + nt) * 512 + lane * 8];
                // scales for this expert (broadcast within quads)
                f32x4 sc[4];
#pragma unroll
                for (int mt = 0; mt < 4; mt++)
                    sc[mt] = *(const f32x4*)&cwT[ne * 132 + wm * 64 + mt * 16 + lq * 4];
                // MFMA + immediate fold (one live f32x4 per chain)
#pragma unroll
                for (int mt = 0; mt < 4; mt++)
#pragma unroll
                    for (int nt = 0; nt < 2; nt++) {
                        f32x4 p = __builtin_amdgcn_mfma_f32_16x16x32_bf16(
                            af[mt][0], bfr[0][nt], fz, 0, 0, 0);
                        p = __builtin_amdgcn_mfma_f32_16x16x32_bf16(
                            af[mt][1], bfr[1][nt], p, 0, 0, 0);
                        acc[mt][nt] += sc[mt] * p;   // v_pk_fma_f32 x2
                    }
            }
            __syncthreads();               // single barrier per 2 experts
        }
    }

    // ---- bias: one MFMA k-step, operands loaded straight to registers ----
    {
        bf16x8 acw[4];
#pragma unroll
        for (int mt = 0; mt < 4; mt++) {
            bf16x8 v;
#pragma unroll
            for (int j = 0; j < 8; j++) v[j] = (bf16)0.f;
            if (lq < 2) {                  // k = lq*8+j in 0..15 real, else 0
                int row = m0 + wm * 64 + mt * 16 + lr;
                f32x4 a = *(const f32x4*)(cw + (size_t)row * NEXP + lq * 8);
                f32x4 b = *(const f32x4*)(cw + (size_t)row * NEXP + lq * 8 + 4);
#pragma unroll
                for (int j = 0; j < 4; j++) { v[j] = (bf16)a[j]; v[4 + j] = (bf16)b[j]; }
            }
            acw[mt] = v;
        }
        bf16x8 bb[2];
#pragma unroll
        for (int nt = 0; nt < 2; nt++) {
            bf16x8 v;
#pragma unroll
            for (int j = 0; j < 8; j++) v[j] = (bf16)0.f;
            if (lq < 2) {
                int col = n0 + wn * 32 + nt * 16 + lr;
#pragma unroll
                for (int j = 0; j < 8; j++)
                    v[j] = (bf16)bias[(size_t)(lq * 8 + j) * OUT_DIM + col];
            }
            bb[nt] = v;
        }
#pragma unroll
        for (int mt = 0; mt < 4; mt++)
#pragma unroll
            for (int nt = 0; nt < 2; nt++)
                acc[mt][nt] = __builtin_amdgcn_mfma_f32_16x16x32_bf16(
                    acw[mt], bb[nt], acc[mt][nt], 0, 0, 0);
    }

    // epilogue: relu + store (C/D: col = lane&15, row = quad*4 + reg)
#pragma unroll
    for (int mt = 0; mt < 4; mt++) {
        int row = m0 + wm * 64 + mt * 16 + lq * 4;
#pragma unroll
        for (int nt = 0; nt < 2; nt++) {
            int col = n0 + wn * 32 + nt * 16 + lr;
#pragma unroll
            for (int r2 = 0; r2 < 4; r2++) {
                float v = acc[mt][nt][r2];
                out[(size_t)(row + r2) * OUT_DIM + col] = v > 0.f ? v : 0.f;
            }
        }
    }
}

// ---------------------------------------------------------------------------
// Insurance fallback if ws_size is too small.
// ---------------------------------------------------------------------------
__global__ void fallback_kernel(const float* __restrict__ x, const float* __restrict__ cw,
                                const float* __restrict__ W, const float* __restrict__ bias,
                                float* __restrict__ out) {
    int o = blockIdx.x * 256 + threadIdx.x;
    int b = o >> 10, oc = o & 1023;
    const float* xr = x + (size_t)b * IN_DIM;
    float accv = 0.f;
    for (int n = 0; n < NEXP; n++) {
        const float* wr = W + (size_t)n * IN_DIM * OUT_DIM + oc;
        float z = 0.f;
        for (int i = 0; i < IN_DIM; i++) z += xr[i] * wr[(size_t)i * OUT_DIM];
        accv += cw[(size_t)b * NEXP + n] * (z + bias[n * OUT_DIM + oc]);
    }
    out[o] = accv > 0.f ? accv : 0.f;
}

extern "C" void kernel_launch(void* const* d_in, const int* in_sizes, int n_in,
                              void* d_out, int out_size, void* d_ws, size_t ws_size,
                              hipStream_t stream) {
    const float* x    = (const float*)d_in[0];
    const float* cw   = (const float*)d_in[1];
    const float* W    = (const float*)d_in[2];
    const float* bias = (const float*)d_in[3];
    float* out = (float*)d_out;

    const size_t wt_elems = (size_t)NEXP * IN_DIM * OUT_DIM;   // 32 MB bf16
    const size_t xt_elems = (size_t)BATCH * IN_DIM;            // 8 MB bf16
    if (ws_size < (wt_elems + xt_elems) * sizeof(bf16)) {
        fallback_kernel<<<(BATCH * OUT_DIM) / 256, 256, 0, stream>>>(x, cw, W, bias, out);
        return;
    }
    bf16* wt = (bf16*)d_ws;
    bf16* xt = wt + wt_elems;

    convert_all<<<4096 + 512, 256, 0, stream>>>(x, W, xt, wt);
    moe_gemm<<<dim3(16, 32), 256, 0, stream>>>(cw, bias, xt, wt, out);
}